// Round 2
// baseline (78313.947 us; speedup 1.0000x reference)
//
#include <hip/hip_runtime.h>
#include <hip/hip_cooperative_groups.h>
#include <stdint.h>

namespace cg = cooperative_groups;

// ---------------------------------------------------------------------------
// LIDM forward: 255 steps x 25-layer stacked LSTM wavefront.
// Round 2: persistent cooperative kernel for the wavefront (558 -> 1 dispatch).
// ---------------------------------------------------------------------------
#ifndef NOISE_VARIANT
#define NOISE_VARIANT 0
#endif

#define S_ 256
#define B_ 64
#define O_ 128
#define L_ 256
#define NL_ 25

// workspace layout (floats)
#define E_MLP_OFF   0            // [S][L][B]   (k slot 0 unused)
#define E_MLP_SZ    (S_*L_*B_)
#define H_STATE_OFF (E_MLP_OFF + E_MLP_SZ)           // [2][NL][L][B]
#define H_STATE_SZ  (2*NL_*L_*B_)
#define C_STATE_OFF (H_STATE_OFF + H_STATE_SZ)       // [NL][L][B]
#define C_STATE_SZ  (NL_*L_*B_)
#define H_EMB_OFF   (C_STATE_OFF + C_STATE_SZ)       // [NL][L][B]
#define H_EMB_SZ    (NL_*L_*B_)
#define HLAST_OFF   (H_EMB_OFF + H_EMB_SZ)           // [S][L][B] (also e1 temp)
#define HLAST_SZ    (S_*L_*B_)
#define WS_FLOATS   (HLAST_OFF + HLAST_SZ)

// ---------------------------- threefry2x32 ---------------------------------
__device__ __forceinline__ uint32_t rotl32(uint32_t v, int r) {
  return (v << r) | (v >> (32 - r));
}

__device__ __forceinline__ void tf2x32(uint32_t k0, uint32_t k1,
                                       uint32_t x0, uint32_t x1,
                                       uint32_t& o0, uint32_t& o1) {
  uint32_t ks2 = k0 ^ k1 ^ 0x1BD11BDAu;
  x0 += k0; x1 += k1;
  x0 += x1; x1 = rotl32(x1, 13); x1 ^= x0;
  x0 += x1; x1 = rotl32(x1, 15); x1 ^= x0;
  x0 += x1; x1 = rotl32(x1, 26); x1 ^= x0;
  x0 += x1; x1 = rotl32(x1,  6); x1 ^= x0;
  x0 += k1; x1 += ks2 + 1u;
  x0 += x1; x1 = rotl32(x1, 17); x1 ^= x0;
  x0 += x1; x1 = rotl32(x1, 29); x1 ^= x0;
  x0 += x1; x1 = rotl32(x1, 16); x1 ^= x0;
  x0 += x1; x1 = rotl32(x1, 24); x1 ^= x0;
  x0 += ks2; x1 += k0 + 2u;
  x0 += x1; x1 = rotl32(x1, 13); x1 ^= x0;
  x0 += x1; x1 = rotl32(x1, 15); x1 ^= x0;
  x0 += x1; x1 = rotl32(x1, 26); x1 ^= x0;
  x0 += x1; x1 = rotl32(x1,  6); x1 ^= x0;
  x0 += k0; x1 += k1 + 3u;
  x0 += x1; x1 = rotl32(x1, 17); x1 ^= x0;
  x0 += x1; x1 = rotl32(x1, 29); x1 ^= x0;
  x0 += x1; x1 = rotl32(x1, 16); x1 ^= x0;
  x0 += x1; x1 = rotl32(x1, 24); x1 ^= x0;
  x0 += k1; x1 += ks2 + 4u;
  x0 += x1; x1 = rotl32(x1, 13); x1 ^= x0;
  x0 += x1; x1 = rotl32(x1, 15); x1 ^= x0;
  x0 += x1; x1 = rotl32(x1, 26); x1 ^= x0;
  x0 += x1; x1 = rotl32(x1,  6); x1 ^= x0;
  o0 = x0 + ks2; o1 = x1 + k0 + 5u;
}

__device__ __forceinline__ void step_keys(int k, uint32_t& kh0, uint32_t& kh1,
                                          uint32_t& kx0, uint32_t& kx1) {
  uint32_t f0, f1;
  tf2x32(0u, 42u, 0u, (uint32_t)k, f0, f1);
#if NOISE_VARIANT == 0
  tf2x32(f0, f1, 0u, 0u, kh0, kh1);
  tf2x32(f0, f1, 0u, 1u, kx0, kx1);
#else
  uint32_t a0, a1, b0, b1;
  tf2x32(f0, f1, 0u, 2u, a0, a1);
  tf2x32(f0, f1, 1u, 3u, b0, b1);
  kh0 = a0; kh1 = b0; kx0 = a1; kx1 = b1;
#endif
}

__device__ __forceinline__ uint32_t rbits(uint32_t key0, uint32_t key1,
                                          uint32_t i, uint32_t total) {
#if NOISE_VARIANT == 0
  uint32_t b0, b1;
  tf2x32(key0, key1, 0u, i, b0, b1);
  (void)total;
  return b0 ^ b1;
#else
  uint32_t half = total >> 1;
  uint32_t x0 = (i < half) ? i : (i - half);
  uint32_t x1 = x0 + half;
  uint32_t b0, b1;
  tf2x32(key0, key1, x0, x1, b0, b1);
  return (i < half) ? b0 : b1;
#endif
}

__device__ __forceinline__ float u32_to_normal(uint32_t bits) {
  const float lo = __uint_as_float(0xBF7FFFFFu);
  float f = __uint_as_float((bits >> 9) | 0x3F800000u) - 1.0f;
  float u = f * 2.0f + lo;
  u = fmaxf(lo, u);
  float x = u;
  float w = -log1pf(-x * x);
  float p;
  if (w < 5.0f) {
    w -= 2.5f;
    p =            2.81022636e-08f;
    p = fmaf(p, w, 3.43273939e-07f);
    p = fmaf(p, w, -3.5233877e-06f);
    p = fmaf(p, w, -4.39150654e-06f);
    p = fmaf(p, w, 0.00021858087f);
    p = fmaf(p, w, -0.00125372503f);
    p = fmaf(p, w, -0.00417768164f);
    p = fmaf(p, w, 0.246640727f);
    p = fmaf(p, w, 1.50140941f);
  } else {
    w = sqrtf(w) - 3.0f;
    p =            -0.000200214257f;
    p = fmaf(p, w, 0.000100950558f);
    p = fmaf(p, w, 0.00134934322f);
    p = fmaf(p, w, -0.00367342844f);
    p = fmaf(p, w, 0.00573950773f);
    p = fmaf(p, w, -0.0076224613f);
    p = fmaf(p, w, 0.00943887047f);
    p = fmaf(p, w, 1.00167406f);
    p = fmaf(p, w, 2.83297682f);
  }
  float ei = p * x;
  return __uint_as_float(0x3FB504F3u) * ei;
}

__device__ __forceinline__ float sigm(float x) { return 1.0f / (1.0f + expf(-x)); }

// ------------------------------- kernels -----------------------------------

__global__ __launch_bounds__(256) void k_init(const float* __restrict__ z0,
                                              float* __restrict__ h_state,
                                              float* __restrict__ c_state) {
  int idx = blockIdx.x * 256 + threadIdx.x;
  int n = idx >> 14;
  int r = idx & 16383;
  int m = r >> 6;
  int b = r & 63;
  h_state[idx] = z0[((size_t)(n * B_ + b)) * L_ + m];
  c_state[idx] = 0.0f;
}

__global__ __launch_bounds__(256) void k_mlp1(const float* __restrict__ obsrv,
                                              const float* __restrict__ Wx1,
                                              const float* __restrict__ bx1,
                                              float* __restrict__ e1out) {
  int k = 1 + (blockIdx.x >> 2);
  int jc = blockIdx.x & 3;
  int lane = threadIdx.x & 63;
  int wv = threadIdx.x >> 6;
  int j0 = jc * 64 + wv * 16;
  const float* xrow = obsrv + ((size_t)k * B_ + lane) * O_;
  float acc[16];
#pragma unroll
  for (int i = 0; i < 16; ++i) acc[i] = 0.0f;
  for (int o = 0; o < O_; o += 4) {
    float4 a = *reinterpret_cast<const float4*>(&xrow[o]);
#pragma unroll
    for (int mi = 0; mi < 16; ++mi) {
      float4 wt = *reinterpret_cast<const float4*>(&Wx1[(size_t)(j0 + mi) * O_ + o]);
      float t = acc[mi];
      t = fmaf(a.x, wt.x, t); t = fmaf(a.y, wt.y, t);
      t = fmaf(a.z, wt.z, t); t = fmaf(a.w, wt.w, t);
      acc[mi] = t;
    }
  }
  float* dst = e1out + (size_t)k * L_ * B_;
#pragma unroll
  for (int mi = 0; mi < 16; ++mi) {
    float v = acc[mi] + bx1[j0 + mi];
    dst[(j0 + mi) * B_ + lane] = fmaxf(v, 0.0f);
  }
}

__global__ __launch_bounds__(256) void k_mlp2(const float* __restrict__ e1buf,
                                              const float* __restrict__ Wx2,
                                              const float* __restrict__ bx2,
                                              const float* __restrict__ Wx3,
                                              const float* __restrict__ bx3,
                                              float* __restrict__ E_mlp) {
  __shared__ float e2s[L_ * B_];
  int k = 1 + blockIdx.x;
  int lane = threadIdx.x & 63;
  int wv = threadIdx.x >> 6;
  const float* e1 = e1buf + (size_t)k * L_ * B_;

  for (int rep = 0; rep < 4; ++rep) {
    int m0 = rep * 64 + wv * 16;
    float acc[16];
#pragma unroll
    for (int i = 0; i < 16; ++i) acc[i] = 0.0f;
    for (int j = 0; j < L_; j += 4) {
      float a0 = e1[(j + 0) * B_ + lane];
      float a1 = e1[(j + 1) * B_ + lane];
      float a2 = e1[(j + 2) * B_ + lane];
      float a3 = e1[(j + 3) * B_ + lane];
#pragma unroll
      for (int mi = 0; mi < 16; ++mi) {
        float4 wt = *reinterpret_cast<const float4*>(&Wx2[(size_t)(m0 + mi) * L_ + j]);
        float t = acc[mi];
        t = fmaf(a0, wt.x, t); t = fmaf(a1, wt.y, t);
        t = fmaf(a2, wt.z, t); t = fmaf(a3, wt.w, t);
        acc[mi] = t;
      }
    }
#pragma unroll
    for (int mi = 0; mi < 16; ++mi) {
      float v = acc[mi] + bx2[m0 + mi];
      e2s[(m0 + mi) * B_ + lane] = fmaxf(v, 0.0f);
    }
  }
  __syncthreads();

  uint32_t kh0, kh1, kx0, kx1;
  step_keys(k, kh0, kh1, kx0, kx1);
  const float sa = sqrtf(0.9f);
  float* dst = E_mlp + (size_t)k * L_ * B_;

  for (int rep = 0; rep < 4; ++rep) {
    int m0 = rep * 64 + wv * 16;
    float acc[16];
#pragma unroll
    for (int i = 0; i < 16; ++i) acc[i] = 0.0f;
    for (int j = 0; j < L_; j += 4) {
      float a0 = e2s[(j + 0) * B_ + lane];
      float a1 = e2s[(j + 1) * B_ + lane];
      float a2 = e2s[(j + 2) * B_ + lane];
      float a3 = e2s[(j + 3) * B_ + lane];
#pragma unroll
      for (int mi = 0; mi < 16; ++mi) {
        float4 wt = *reinterpret_cast<const float4*>(&Wx3[(size_t)(m0 + mi) * L_ + j]);
        float t = acc[mi];
        t = fmaf(a0, wt.x, t); t = fmaf(a1, wt.y, t);
        t = fmaf(a2, wt.z, t); t = fmaf(a3, wt.w, t);
        acc[mi] = t;
      }
    }
#pragma unroll
    for (int mi = 0; mi < 16; ++mi) {
      int m = m0 + mi;
      uint32_t bits = rbits(kx0, kx1, (uint32_t)(lane * L_ + m), (uint32_t)(B_ * L_));
      float nz = u32_to_normal(bits);
      float v = acc[mi] + bx3[m];
      dst[m * B_ + lane] = sa * v + 0.1f * nz;
    }
  }
}

// Persistent wavefront kernel: 400 blocks x 256 threads, 2 blocks/CU.
// Per diagonal d: phase A (emb+noise, nc*16 blocks x 16 rows) -> grid.sync()
//                 phase B (gates+activations, nc*16 blocks)   -> grid.sync()
__global__ __launch_bounds__(256, 2) void k_wave(float* __restrict__ h_state,
                                                 float* __restrict__ c_state,
                                                 float* __restrict__ h_emb,
                                                 const float* __restrict__ E_mlp,
                                                 const float* __restrict__ W_emb,
                                                 const float* __restrict__ b_emb,
                                                 const float* __restrict__ W_ih,
                                                 const float* __restrict__ W_hh,
                                                 const float* __restrict__ b_ih,
                                                 const float* __restrict__ b_hh,
                                                 float* __restrict__ Hlast) {
  cg::grid_group grid = cg::this_grid();
  int bid = blockIdx.x;          // 0..399
  int lane = threadIdx.x & 63;
  int wv = threadIdx.x >> 6;

  for (int d = 1; d <= S_ - 1 + NL_ - 1; ++d) {
    int lmin = (d - (S_ - 1) > 0) ? (d - (S_ - 1)) : 0;
    int lmax = (d - 1 < NL_ - 1) ? (d - 1) : (NL_ - 1);
    int nc = lmax - lmin + 1;

    // ---- phase A: h_emb[l] = h_prev[l] @ W_emb^T + b_emb + 0.1*noise(kh) ----
    if (bid < nc * 16) {
      int l = lmin + (bid >> 4);
      int k = d - l;
      int m0 = (bid & 15) * 16 + wv * 4;
      const float* hsrc = h_state + ((size_t)((k - 1) & 1) * NL_ + l) * (L_ * B_);
      float acc[4] = {0.0f, 0.0f, 0.0f, 0.0f};
      for (int j = 0; j < L_; j += 4) {
        float a0 = hsrc[(j + 0) * B_ + lane];
        float a1 = hsrc[(j + 1) * B_ + lane];
        float a2 = hsrc[(j + 2) * B_ + lane];
        float a3 = hsrc[(j + 3) * B_ + lane];
#pragma unroll
        for (int mi = 0; mi < 4; ++mi) {
          float4 wt = *reinterpret_cast<const float4*>(&W_emb[(size_t)(m0 + mi) * L_ + j]);
          float t = acc[mi];
          t = fmaf(a0, wt.x, t); t = fmaf(a1, wt.y, t);
          t = fmaf(a2, wt.z, t); t = fmaf(a3, wt.w, t);
          acc[mi] = t;
        }
      }
      uint32_t kh0, kh1, kx0, kx1;
      step_keys(k, kh0, kh1, kx0, kx1);
      float* dst = h_emb + (size_t)l * L_ * B_;
#pragma unroll
      for (int mi = 0; mi < 4; ++mi) {
        int m = m0 + mi;
        uint32_t i = ((uint32_t)(l * B_ + lane)) * L_ + (uint32_t)m;
        float nz = u32_to_normal(rbits(kh0, kh1, i, (uint32_t)(NL_ * B_ * L_)));
        dst[m * B_ + lane] = acc[mi] + b_emb[m] + 0.1f * nz;
      }
    }
    grid.sync();

    // ---- phase B: gates + activations ----
    if (bid < nc * 16) {
      int l = lmin + (bid >> 4);
      int k = d - l;
      int mc = bid & 15;
      int m0 = mc * 16 + wv * 4;

      float acc[4][4];
#pragma unroll
      for (int g = 0; g < 4; ++g)
#pragma unroll
        for (int mi = 0; mi < 4; ++mi) acc[g][mi] = 0.0f;

      const float* ein = (l == 0)
          ? (E_mlp + (size_t)k * L_ * B_)
          : (h_state + ((size_t)(k & 1) * NL_ + (l - 1)) * (L_ * B_));
      const float* Wl = W_ih + (size_t)l * 4 * L_ * L_;
      for (int j = 0; j < L_; j += 4) {
        float a0 = ein[(j + 0) * B_ + lane];
        float a1 = ein[(j + 1) * B_ + lane];
        float a2 = ein[(j + 2) * B_ + lane];
        float a3 = ein[(j + 3) * B_ + lane];
#pragma unroll
        for (int g = 0; g < 4; ++g)
#pragma unroll
          for (int mi = 0; mi < 4; ++mi) {
            float4 wt = *reinterpret_cast<const float4*>(&Wl[(size_t)(g * L_ + m0 + mi) * L_ + j]);
            float t = acc[g][mi];
            t = fmaf(a0, wt.x, t); t = fmaf(a1, wt.y, t);
            t = fmaf(a2, wt.z, t); t = fmaf(a3, wt.w, t);
            acc[g][mi] = t;
          }
      }
      const float* hem = h_emb + (size_t)l * L_ * B_;
      const float* Wl2 = W_hh + (size_t)l * 4 * L_ * L_;
      for (int j = 0; j < L_; j += 4) {
        float a0 = hem[(j + 0) * B_ + lane];
        float a1 = hem[(j + 1) * B_ + lane];
        float a2 = hem[(j + 2) * B_ + lane];
        float a3 = hem[(j + 3) * B_ + lane];
#pragma unroll
        for (int g = 0; g < 4; ++g)
#pragma unroll
          for (int mi = 0; mi < 4; ++mi) {
            float4 wt = *reinterpret_cast<const float4*>(&Wl2[(size_t)(g * L_ + m0 + mi) * L_ + j]);
            float t = acc[g][mi];
            t = fmaf(a0, wt.x, t); t = fmaf(a1, wt.y, t);
            t = fmaf(a2, wt.z, t); t = fmaf(a3, wt.w, t);
            acc[g][mi] = t;
          }
      }

      int bb = l * 4 * L_;
      float* hdst = h_state + ((size_t)(k & 1) * NL_ + l) * (L_ * B_);
#pragma unroll
      for (int mi = 0; mi < 4; ++mi) {
        int m = m0 + mi;
        float iv = acc[0][mi] + b_ih[bb + m]           + b_hh[bb + m];
        float fv = acc[1][mi] + b_ih[bb + L_ + m]      + b_hh[bb + L_ + m];
        float gv = acc[2][mi] + b_ih[bb + 2 * L_ + m]  + b_hh[bb + 2 * L_ + m];
        float ov = acc[3][mi] + b_ih[bb + 3 * L_ + m]  + b_hh[bb + 3 * L_ + m];
        size_t idx = ((size_t)l * L_ + m) * B_ + lane;
        float co = c_state[idx];
        float cn = sigm(fv) * co + sigm(iv) * tanhf(gv);
        float hn = sigm(ov) * tanhf(cn);
        c_state[idx] = cn;
        hdst[m * B_ + lane] = hn;
        if (l == NL_ - 1) Hlast[((size_t)k * L_ + m) * B_ + lane] = hn;
      }
    }
    grid.sync();
  }
}

__global__ __launch_bounds__(256) void k_final(const float* __restrict__ Hlast,
                                               const float* __restrict__ W_out,
                                               const float* __restrict__ b_out,
                                               float* __restrict__ out) {
  int k = blockIdx.x >> 2;
  int mc = blockIdx.x & 3;
  int lane = threadIdx.x & 63;
  int wv = threadIdx.x >> 6;
  int m0 = mc * 64 + wv * 16;
  float res[16];
  if (k == 0) {
#pragma unroll
    for (int mi = 0; mi < 16; ++mi) res[mi] = 0.0f;
  } else {
    float acc[16];
#pragma unroll
    for (int i = 0; i < 16; ++i) acc[i] = 0.0f;
    const float* src = Hlast + (size_t)k * L_ * B_;
    for (int j = 0; j < L_; j += 4) {
      float a0 = src[(j + 0) * B_ + lane];
      float a1 = src[(j + 1) * B_ + lane];
      float a2 = src[(j + 2) * B_ + lane];
      float a3 = src[(j + 3) * B_ + lane];
#pragma unroll
      for (int mi = 0; mi < 16; ++mi) {
        float4 wt = *reinterpret_cast<const float4*>(&W_out[(size_t)(m0 + mi) * L_ + j]);
        float t = acc[mi];
        t = fmaf(a0, wt.x, t); t = fmaf(a1, wt.y, t);
        t = fmaf(a2, wt.z, t); t = fmaf(a3, wt.w, t);
        acc[mi] = t;
      }
    }
#pragma unroll
    for (int mi = 0; mi < 16; ++mi) res[mi] = acc[mi] + b_out[m0 + mi];
  }
  float* dst = out + ((size_t)k * B_ + lane) * L_ + m0;
#pragma unroll
  for (int v = 0; v < 4; ++v) {
    float4 t4 = make_float4(res[4 * v], res[4 * v + 1], res[4 * v + 2], res[4 * v + 3]);
    *reinterpret_cast<float4*>(&dst[4 * v]) = t4;
  }
}

// ------------------------------ launcher -----------------------------------
extern "C" void kernel_launch(void* const* d_in, const int* in_sizes, int n_in,
                              void* d_out, int out_size, void* d_ws, size_t ws_size,
                              hipStream_t stream) {
  const float* obsrv = (const float*)d_in[0];
  const float* z0    = (const float*)d_in[1];
  const float* W_emb = (const float*)d_in[2];
  const float* b_emb = (const float*)d_in[3];
  const float* Wx1   = (const float*)d_in[4];
  const float* bx1   = (const float*)d_in[5];
  const float* Wx2   = (const float*)d_in[6];
  const float* bx2   = (const float*)d_in[7];
  const float* Wx3   = (const float*)d_in[8];
  const float* bx3   = (const float*)d_in[9];
  const float* W_ih  = (const float*)d_in[10];
  const float* W_hh  = (const float*)d_in[11];
  const float* b_ih  = (const float*)d_in[12];
  const float* b_hh  = (const float*)d_in[13];
  const float* W_out = (const float*)d_in[14];
  const float* b_out = (const float*)d_in[15];
  float* out = (float*)d_out;
  float* ws = (float*)d_ws;

  if (ws_size < (size_t)WS_FLOATS * sizeof(float)) return;

  float* E_mlp   = ws + E_MLP_OFF;
  float* h_state = ws + H_STATE_OFF;
  float* c_state = ws + C_STATE_OFF;
  float* h_emb   = ws + H_EMB_OFF;
  float* Hlast   = ws + HLAST_OFF;

  k_init<<<(NL_ * L_ * B_) / 256, 256, 0, stream>>>(z0, h_state, c_state);
  k_mlp1<<<255 * 4, 256, 0, stream>>>(obsrv, Wx1, bx1, Hlast);  // Hlast as e1 temp
  k_mlp2<<<255, 256, 0, stream>>>(Hlast, Wx2, bx2, Wx3, bx3, E_mlp);

  void* args[] = {(void*)&h_state, (void*)&c_state, (void*)&h_emb, (void*)&E_mlp,
                  (void*)&W_emb, (void*)&b_emb, (void*)&W_ih, (void*)&W_hh,
                  (void*)&b_ih, (void*)&b_hh, (void*)&Hlast};
  hipLaunchCooperativeKernel((const void*)k_wave, dim3(400), dim3(256),
                             args, 0, stream);

  k_final<<<S_ * 4, 256, 0, stream>>>(Hlast, W_out, b_out, out);
}

// Round 3
// 18802.405 us; speedup vs baseline: 4.1651x; 4.1651x over previous
//
#include <hip/hip_runtime.h>
#include <hip/hip_cooperative_groups.h>
#include <stdint.h>

namespace cg = cooperative_groups;

// ---------------------------------------------------------------------------
// LIDM forward, round 3: persistent coop wavefront with LDS-resident bf16
// weights + MFMA 32x32x16. Static block=(layer l, m-slice s) mapping.
// ---------------------------------------------------------------------------
#ifndef NOISE_VARIANT
#define NOISE_VARIANT 0
#endif

#define S_ 256
#define B_ 64
#define O_ 128
#define L_ 256
#define NL_ 25

typedef __attribute__((ext_vector_type(8))) short short8v;
typedef __attribute__((ext_vector_type(16))) float f32x16;

// ---- workspace byte offsets ----
#define HLAST_B   0u                 // f32 [256][256][64] (also e1 temp f32 [k][j][b])
#define EMLP_B    16777216u          // u16 [256][64][256]
#define HSTATE_B  25165824u          // u16 [2][25][64][256]
#define HEMB_B    26804224u          // u16 [25][64][256]
#define CSTATE_B  27623424u          // f32 [25][256][64]
#define WS_END    29261824u

// ---------------------------- helpers --------------------------------------
__device__ __forceinline__ uint16_t f2bf(float x) {
  uint32_t u = __float_as_uint(x);
  return (uint16_t)((u + 0x7fffu + ((u >> 16) & 1u)) >> 16);
}

__device__ __forceinline__ uint32_t rotl32(uint32_t v, int r) {
  return (v << r) | (v >> (32 - r));
}

__device__ __forceinline__ void tf2x32(uint32_t k0, uint32_t k1,
                                       uint32_t x0, uint32_t x1,
                                       uint32_t& o0, uint32_t& o1) {
  uint32_t ks2 = k0 ^ k1 ^ 0x1BD11BDAu;
  x0 += k0; x1 += k1;
  x0 += x1; x1 = rotl32(x1, 13); x1 ^= x0;
  x0 += x1; x1 = rotl32(x1, 15); x1 ^= x0;
  x0 += x1; x1 = rotl32(x1, 26); x1 ^= x0;
  x0 += x1; x1 = rotl32(x1,  6); x1 ^= x0;
  x0 += k1; x1 += ks2 + 1u;
  x0 += x1; x1 = rotl32(x1, 17); x1 ^= x0;
  x0 += x1; x1 = rotl32(x1, 29); x1 ^= x0;
  x0 += x1; x1 = rotl32(x1, 16); x1 ^= x0;
  x0 += x1; x1 = rotl32(x1, 24); x1 ^= x0;
  x0 += ks2; x1 += k0 + 2u;
  x0 += x1; x1 = rotl32(x1, 13); x1 ^= x0;
  x0 += x1; x1 = rotl32(x1, 15); x1 ^= x0;
  x0 += x1; x1 = rotl32(x1, 26); x1 ^= x0;
  x0 += x1; x1 = rotl32(x1,  6); x1 ^= x0;
  x0 += k0; x1 += k1 + 3u;
  x0 += x1; x1 = rotl32(x1, 17); x1 ^= x0;
  x0 += x1; x1 = rotl32(x1, 29); x1 ^= x0;
  x0 += x1; x1 = rotl32(x1, 16); x1 ^= x0;
  x0 += x1; x1 = rotl32(x1, 24); x1 ^= x0;
  x0 += k1; x1 += ks2 + 4u;
  x0 += x1; x1 = rotl32(x1, 13); x1 ^= x0;
  x0 += x1; x1 = rotl32(x1, 15); x1 ^= x0;
  x0 += x1; x1 = rotl32(x1, 26); x1 ^= x0;
  x0 += x1; x1 = rotl32(x1,  6); x1 ^= x0;
  o0 = x0 + ks2; o1 = x1 + k0 + 5u;
}

__device__ __forceinline__ void step_keys(int k, uint32_t& kh0, uint32_t& kh1,
                                          uint32_t& kx0, uint32_t& kx1) {
  uint32_t f0, f1;
  tf2x32(0u, 42u, 0u, (uint32_t)k, f0, f1);
#if NOISE_VARIANT == 0
  tf2x32(f0, f1, 0u, 0u, kh0, kh1);
  tf2x32(f0, f1, 0u, 1u, kx0, kx1);
#else
  uint32_t a0, a1, b0, b1;
  tf2x32(f0, f1, 0u, 2u, a0, a1);
  tf2x32(f0, f1, 1u, 3u, b0, b1);
  kh0 = a0; kh1 = b0; kx0 = a1; kx1 = b1;
#endif
}

__device__ __forceinline__ uint32_t rbits(uint32_t key0, uint32_t key1,
                                          uint32_t i, uint32_t total) {
#if NOISE_VARIANT == 0
  uint32_t b0, b1;
  tf2x32(key0, key1, 0u, i, b0, b1);
  (void)total;
  return b0 ^ b1;
#else
  uint32_t half = total >> 1;
  uint32_t x0 = (i < half) ? i : (i - half);
  uint32_t x1 = x0 + half;
  uint32_t b0, b1;
  tf2x32(key0, key1, x0, x1, b0, b1);
  return (i < half) ? b0 : b1;
#endif
}

__device__ __forceinline__ float u32_to_normal(uint32_t bits) {
  const float lo = __uint_as_float(0xBF7FFFFFu);
  float f = __uint_as_float((bits >> 9) | 0x3F800000u) - 1.0f;
  float u = f * 2.0f + lo;
  u = fmaxf(lo, u);
  float x = u;
  float w = -log1pf(-x * x);
  float p;
  if (w < 5.0f) {
    w -= 2.5f;
    p =            2.81022636e-08f;
    p = fmaf(p, w, 3.43273939e-07f);
    p = fmaf(p, w, -3.5233877e-06f);
    p = fmaf(p, w, -4.39150654e-06f);
    p = fmaf(p, w, 0.00021858087f);
    p = fmaf(p, w, -0.00125372503f);
    p = fmaf(p, w, -0.00417768164f);
    p = fmaf(p, w, 0.246640727f);
    p = fmaf(p, w, 1.50140941f);
  } else {
    w = sqrtf(w) - 3.0f;
    p =            -0.000200214257f;
    p = fmaf(p, w, 0.000100950558f);
    p = fmaf(p, w, 0.00134934322f);
    p = fmaf(p, w, -0.00367342844f);
    p = fmaf(p, w, 0.00573950773f);
    p = fmaf(p, w, -0.0076224613f);
    p = fmaf(p, w, 0.00943887047f);
    p = fmaf(p, w, 1.00167406f);
    p = fmaf(p, w, 2.83297682f);
  }
  return __uint_as_float(0x3FB504F3u) * (p * x);
}

__device__ __forceinline__ float sigm(float x) { return 1.0f / (1.0f + expf(-x)); }

// ------------------------------- kernels -----------------------------------

// h_state[0][l][b][j] = bf16(z0[l][b][j]); c_state = 0  (layouts match flat)
__global__ __launch_bounds__(256) void k_init(const float* __restrict__ z0,
                                              uint16_t* __restrict__ hs0,
                                              float* __restrict__ c_state) {
  int idx = blockIdx.x * 256 + threadIdx.x;  // 0..409599
  hs0[idx] = f2bf(z0[idx]);
  c_state[idx] = 0.0f;
}

// e1[k][j][b] = relu(obsrv[k] @ Wx1^T + bx1)  fp32, grid 255*4
__global__ __launch_bounds__(256) void k_mlp1(const float* __restrict__ obsrv,
                                              const float* __restrict__ Wx1,
                                              const float* __restrict__ bx1,
                                              float* __restrict__ e1out) {
  int k = 1 + (blockIdx.x >> 2);
  int jc = blockIdx.x & 3;
  int lane = threadIdx.x & 63;
  int wv = threadIdx.x >> 6;
  int j0 = jc * 64 + wv * 16;
  const float* xrow = obsrv + ((size_t)k * B_ + lane) * O_;
  float acc[16];
#pragma unroll
  for (int i = 0; i < 16; ++i) acc[i] = 0.0f;
  for (int o = 0; o < O_; o += 4) {
    float4 a = *reinterpret_cast<const float4*>(&xrow[o]);
#pragma unroll
    for (int mi = 0; mi < 16; ++mi) {
      float4 wt = *reinterpret_cast<const float4*>(&Wx1[(size_t)(j0 + mi) * O_ + o]);
      float t = acc[mi];
      t = fmaf(a.x, wt.x, t); t = fmaf(a.y, wt.y, t);
      t = fmaf(a.z, wt.z, t); t = fmaf(a.w, wt.w, t);
      acc[mi] = t;
    }
  }
  float* dst = e1out + (size_t)k * L_ * B_;
#pragma unroll
  for (int mi = 0; mi < 16; ++mi) {
    float v = acc[mi] + bx1[j0 + mi];
    dst[(j0 + mi) * B_ + lane] = fmaxf(v, 0.0f);
  }
}

// MLP layers 2,3 + sqrt(alpha)*e + 0.1*noise -> E_mlp bf16 [k][b][j]
__global__ __launch_bounds__(256) void k_mlp2(const float* __restrict__ e1buf,
                                              const float* __restrict__ Wx2,
                                              const float* __restrict__ bx2,
                                              const float* __restrict__ Wx3,
                                              const float* __restrict__ bx3,
                                              uint16_t* __restrict__ E_mlp) {
  __shared__ float e2s[L_ * B_];
  int k = 1 + blockIdx.x;
  int lane = threadIdx.x & 63;
  int wv = threadIdx.x >> 6;
  const float* e1 = e1buf + (size_t)k * L_ * B_;

  for (int rep = 0; rep < 4; ++rep) {
    int m0 = rep * 64 + wv * 16;
    float acc[16];
#pragma unroll
    for (int i = 0; i < 16; ++i) acc[i] = 0.0f;
    for (int j = 0; j < L_; j += 4) {
      float a0 = e1[(j + 0) * B_ + lane];
      float a1 = e1[(j + 1) * B_ + lane];
      float a2 = e1[(j + 2) * B_ + lane];
      float a3 = e1[(j + 3) * B_ + lane];
#pragma unroll
      for (int mi = 0; mi < 16; ++mi) {
        float4 wt = *reinterpret_cast<const float4*>(&Wx2[(size_t)(m0 + mi) * L_ + j]);
        float t = acc[mi];
        t = fmaf(a0, wt.x, t); t = fmaf(a1, wt.y, t);
        t = fmaf(a2, wt.z, t); t = fmaf(a3, wt.w, t);
        acc[mi] = t;
      }
    }
#pragma unroll
    for (int mi = 0; mi < 16; ++mi) {
      float v = acc[mi] + bx2[m0 + mi];
      e2s[(m0 + mi) * B_ + lane] = fmaxf(v, 0.0f);
    }
  }
  __syncthreads();

  uint32_t kh0, kh1, kx0, kx1;
  step_keys(k, kh0, kh1, kx0, kx1);
  const float sa = sqrtf(0.9f);

  for (int rep = 0; rep < 4; ++rep) {
    int m0 = rep * 64 + wv * 16;
    float acc[16];
#pragma unroll
    for (int i = 0; i < 16; ++i) acc[i] = 0.0f;
    for (int j = 0; j < L_; j += 4) {
      float a0 = e2s[(j + 0) * B_ + lane];
      float a1 = e2s[(j + 1) * B_ + lane];
      float a2 = e2s[(j + 2) * B_ + lane];
      float a3 = e2s[(j + 3) * B_ + lane];
#pragma unroll
      for (int mi = 0; mi < 16; ++mi) {
        float4 wt = *reinterpret_cast<const float4*>(&Wx3[(size_t)(m0 + mi) * L_ + j]);
        float t = acc[mi];
        t = fmaf(a0, wt.x, t); t = fmaf(a1, wt.y, t);
        t = fmaf(a2, wt.z, t); t = fmaf(a3, wt.w, t);
        acc[mi] = t;
      }
    }
    uint16_t tmp[16];
#pragma unroll
    for (int mi = 0; mi < 16; ++mi) {
      int m = m0 + mi;
      uint32_t bits = rbits(kx0, kx1, (uint32_t)(lane * L_ + m), (uint32_t)(B_ * L_));
      float nz = u32_to_normal(bits);
      tmp[mi] = f2bf(sa * (acc[mi] + bx3[m]) + 0.1f * nz);
    }
    // E_mlp[k][b=lane][m0..m0+15]
    uint16_t* dst = E_mlp + ((size_t)k * B_ + lane) * L_ + m0;
    *reinterpret_cast<uint4*>(dst) = *reinterpret_cast<const uint4*>(&tmp[0]);
    *reinterpret_cast<uint4*>(dst + 8) = *reinterpret_cast<const uint4*>(&tmp[8]);
  }
}

// ---- LDS geometry for k_wave ----
// WG  (gates weights):  128 rows x 1024 B (bf16 k=0..511), XOR-swizzled -> 131072 B
// WE  (emb weights):     32 rows x  512 B (bf16 k=0..255), XOR-swizzled ->  16384 B
// BT  (B-tile dbuf):   2 x 64 rows x 80 B ([b][kk 0..31] bf16, padded)  ->  10240 B
#define WG_OFF 0
#define WE_OFF 131072
#define BT_OFF 147456
#define BT_SZ  5120
#define SMEM_SZ 157696

__device__ __forceinline__ void stage_tile(unsigned char* dst,
                                           const uint16_t* __restrict__ src,
                                           int k0, int t) {
  if (t < 256) {
    int b = t >> 2, q = t & 3;
    uint4 v = *reinterpret_cast<const uint4*>(src + (size_t)b * 256 + k0 + q * 8);
    *reinterpret_cast<uint4*>(dst + b * 80 + q * 16) = v;
  }
}

// Persistent wavefront: 200 blocks x 512 threads, block = (l = bid>>3, s = bid&7).
__global__ __launch_bounds__(512) void k_wave(const float* __restrict__ W_emb,
                                              const float* __restrict__ b_emb,
                                              const float* __restrict__ W_ih,
                                              const float* __restrict__ W_hh,
                                              const float* __restrict__ b_ih,
                                              const float* __restrict__ b_hh,
                                              uint16_t* __restrict__ hstate,
                                              uint16_t* __restrict__ hemb,
                                              const uint16_t* __restrict__ emlp,
                                              float* __restrict__ cstate,
                                              float* __restrict__ hlast) {
  cg::grid_group grid = cg::this_grid();
  __shared__ __align__(16) unsigned char smem[SMEM_SZ];

  const int bid = blockIdx.x;
  const int l = bid >> 3;
  const int s = bid & 7;
  const int t = threadIdx.x;
  const int lane = t & 63;
  const int wid = t >> 6;
  const int lo5 = lane & 31;   // row/col within 32-tile
  const int hi = lane >> 5;    // k-half selector
  const int tm = wid >> 1;     // gates M-tile (0..3)
  const int tn = wid & 1;      // N-tile (0..1)

  // ---- pack weight slices into LDS (once) ----
  // gates rows: r = tm*32 + tr; gate g = tr&3; mi_local = tm*8 + (tr>>2)
  for (int it = 0; it < 16; ++it) {
    int cid = t + it * 512;          // 0..8191
    int r = cid >> 6, cc = cid & 63; // 64 x 16B chunks per row
    int tr = r & 31;
    int g = tr & 3;
    int mi = s * 32 + (r >> 5) * 8 + (tr >> 2);
    int k8 = cc * 8;
    const float* srow = (k8 < 256)
        ? (W_ih + ((size_t)l * 1024 + g * 256 + mi) * 256 + k8)
        : (W_hh + ((size_t)l * 1024 + g * 256 + mi) * 256 + (k8 - 256));
    float4 f0 = *reinterpret_cast<const float4*>(srow);
    float4 f1 = *reinterpret_cast<const float4*>(srow + 4);
    short8v w;
    w[0] = (short)f2bf(f0.x); w[1] = (short)f2bf(f0.y);
    w[2] = (short)f2bf(f0.z); w[3] = (short)f2bf(f0.w);
    w[4] = (short)f2bf(f1.x); w[5] = (short)f2bf(f1.y);
    w[6] = (short)f2bf(f1.z); w[7] = (short)f2bf(f1.w);
    int byte = r * 1024 + ((cc * 16) ^ ((r & 7) << 4));
    *reinterpret_cast<short8v*>(smem + WG_OFF + byte) = w;
  }
  // emb rows: r 0..31 = W_emb[s*32 + r]
  for (int it = 0; it < 2; ++it) {
    int cid = t + it * 512;          // 0..1023
    int r = cid >> 5, cc = cid & 31;
    const float* srow = W_emb + ((size_t)(s * 32 + r)) * 256 + cc * 8;
    float4 f0 = *reinterpret_cast<const float4*>(srow);
    float4 f1 = *reinterpret_cast<const float4*>(srow + 4);
    short8v w;
    w[0] = (short)f2bf(f0.x); w[1] = (short)f2bf(f0.y);
    w[2] = (short)f2bf(f0.z); w[3] = (short)f2bf(f0.w);
    w[4] = (short)f2bf(f1.x); w[5] = (short)f2bf(f1.y);
    w[6] = (short)f2bf(f1.z); w[7] = (short)f2bf(f1.w);
    int byte = r * 512 + ((cc * 16) ^ ((r & 7) << 4));
    *reinterpret_cast<short8v*>(smem + WE_OFF + byte) = w;
  }
  __syncthreads();

  unsigned char* bt[2] = {smem + BT_OFF, smem + BT_OFF + BT_SZ};

  for (int d = 1; d <= S_ - 1 + NL_ - 1; ++d) {
    const int k = d - l;
    const bool active = (k >= 1 && k <= S_ - 1);

    // ================= phase 1: h_emb[l] = W_emb @ h(k-1,l) + b + noise ====
    if (active) {
      const uint16_t* hprev = hstate + (((size_t)((k - 1) & 1) * NL_ + l) << 14);
      stage_tile(bt[0], hprev, 0, t);
      __syncthreads();
      f32x16 acc = {0,0,0,0,0,0,0,0,0,0,0,0,0,0,0,0};
      for (int kt = 0; kt < 8; ++kt) {
        if (kt < 7) stage_tile(bt[(kt + 1) & 1], hprev, (kt + 1) * 32, t);
        if (wid < 2) {
          const unsigned char* bb = bt[kt & 1];
#pragma unroll
          for (int kh = 0; kh < 2; ++kh) {
            int abyte = lo5 * 512 + ((kt * 64 + kh * 32 + hi * 16) ^ ((lo5 & 7) << 4));
            short8v a = *reinterpret_cast<const short8v*>(smem + WE_OFF + abyte);
            short8v b = *reinterpret_cast<const short8v*>(bb + (wid * 32 + lo5) * 80 + kh * 32 + hi * 16);
            acc = __builtin_amdgcn_mfma_f32_32x32x16_bf16(a, b, acc, 0, 0, 0);
          }
        }
        __syncthreads();
      }
      if (wid < 2) {
        uint32_t kh0, kh1, kx0, kx1;
        step_keys(k, kh0, kh1, kx0, kx1);
        int b = wid * 32 + lo5;
#pragma unroll
        for (int reg = 0; reg < 16; ++reg) {
          int tr = (reg & 3) + 8 * (reg >> 2) + 4 * hi;
          int j = s * 32 + tr;
          uint32_t i = ((uint32_t)(l * 64 + b)) * 256 + (uint32_t)j;
          float nz = u32_to_normal(rbits(kh0, kh1, i, (uint32_t)(NL_ * B_ * L_)));
          float v = acc[reg] + b_emb[j] + 0.1f * nz;
          hemb[((size_t)l * 64 + b) * 256 + j] = f2bf(v);
        }
      }
    }
    grid.sync();

    // ================= phase 2: gates + LSTM update ========================
    if (active) {
      const uint16_t* ein = (l == 0)
          ? (emlp + ((size_t)k << 14))
          : (hstate + (((size_t)(k & 1) * NL_ + (l - 1)) << 14));
      const uint16_t* hem = hemb + ((size_t)l << 14);
      stage_tile(bt[0], ein, 0, t);
      __syncthreads();
      f32x16 acc = {0,0,0,0,0,0,0,0,0,0,0,0,0,0,0,0};
      const int r = tm * 32 + lo5;
      const int rswz = (r & 7) << 4;
      for (int kt = 0; kt < 16; ++kt) {
        if (kt < 15) {
          const uint16_t* src = (kt + 1 < 8) ? ein : hem;
          stage_tile(bt[(kt + 1) & 1], src, ((kt + 1) & 7) * 32, t);
        }
        const unsigned char* bb = bt[kt & 1];
#pragma unroll
        for (int kh = 0; kh < 2; ++kh) {
          int abyte = r * 1024 + ((kt * 64 + kh * 32 + hi * 16) ^ rswz);
          short8v a = *reinterpret_cast<const short8v*>(smem + WG_OFF + abyte);
          short8v b = *reinterpret_cast<const short8v*>(bb + (tn * 32 + lo5) * 80 + kh * 32 + hi * 16);
          acc = __builtin_amdgcn_mfma_f32_32x32x16_bf16(a, b, acc, 0, 0, 0);
        }
        __syncthreads();
      }
      // epilogue: lane holds all 4 gates for 4 mi values, col b
      const int b = tn * 32 + lo5;
      const int par = k & 1;
      uint16_t* hdst = hstate + (((size_t)par * NL_ + l) << 14);
#pragma unroll
      for (int mq = 0; mq < 4; ++mq) {
        int mi = s * 32 + tm * 8 + mq * 2 + hi;
        float iv = acc[mq * 4 + 0] + b_ih[l * 1024 + 0 * 256 + mi] + b_hh[l * 1024 + 0 * 256 + mi];
        float fv = acc[mq * 4 + 1] + b_ih[l * 1024 + 1 * 256 + mi] + b_hh[l * 1024 + 1 * 256 + mi];
        float gv = acc[mq * 4 + 2] + b_ih[l * 1024 + 2 * 256 + mi] + b_hh[l * 1024 + 2 * 256 + mi];
        float ov = acc[mq * 4 + 3] + b_ih[l * 1024 + 3 * 256 + mi] + b_hh[l * 1024 + 3 * 256 + mi];
        size_t cidx = ((size_t)l * 256 + mi) * 64 + b;
        float co = cstate[cidx];
        float cn = sigm(fv) * co + sigm(iv) * tanhf(gv);
        float hn = sigm(ov) * tanhf(cn);
        cstate[cidx] = cn;
        hdst[(size_t)b * 256 + mi] = f2bf(hn);
        if (l == NL_ - 1) hlast[((size_t)k * 256 + mi) * 64 + b] = hn;
      }
    }
    grid.sync();
  }
}

// out[k][b][m] = Hlast[k] @ W_out^T + b_out ; out[0] = 0
__global__ __launch_bounds__(256) void k_final(const float* __restrict__ Hlast,
                                               const float* __restrict__ W_out,
                                               const float* __restrict__ b_out,
                                               float* __restrict__ out) {
  int k = blockIdx.x >> 2;
  int mc = blockIdx.x & 3;
  int lane = threadIdx.x & 63;
  int wv = threadIdx.x >> 6;
  int m0 = mc * 64 + wv * 16;
  float res[16];
  if (k == 0) {
#pragma unroll
    for (int mi = 0; mi < 16; ++mi) res[mi] = 0.0f;
  } else {
    float acc[16];
#pragma unroll
    for (int i = 0; i < 16; ++i) acc[i] = 0.0f;
    const float* src = Hlast + (size_t)k * L_ * B_;
    for (int j = 0; j < L_; j += 4) {
      float a0 = src[(j + 0) * B_ + lane];
      float a1 = src[(j + 1) * B_ + lane];
      float a2 = src[(j + 2) * B_ + lane];
      float a3 = src[(j + 3) * B_ + lane];
#pragma unroll
      for (int mi = 0; mi < 16; ++mi) {
        float4 wt = *reinterpret_cast<const float4*>(&W_out[(size_t)(m0 + mi) * L_ + j]);
        float t = acc[mi];
        t = fmaf(a0, wt.x, t); t = fmaf(a1, wt.y, t);
        t = fmaf(a2, wt.z, t); t = fmaf(a3, wt.w, t);
        acc[mi] = t;
      }
    }
#pragma unroll
    for (int mi = 0; mi < 16; ++mi) res[mi] = acc[mi] + b_out[m0 + mi];
  }
  float* dst = out + ((size_t)k * B_ + lane) * L_ + m0;
#pragma unroll
  for (int v = 0; v < 4; ++v) {
    float4 t4 = make_float4(res[4 * v], res[4 * v + 1], res[4 * v + 2], res[4 * v + 3]);
    *reinterpret_cast<float4*>(&dst[4 * v]) = t4;
  }
}

// ------------------------------ launcher -----------------------------------
extern "C" void kernel_launch(void* const* d_in, const int* in_sizes, int n_in,
                              void* d_out, int out_size, void* d_ws, size_t ws_size,
                              hipStream_t stream) {
  const float* obsrv = (const float*)d_in[0];
  const float* z0    = (const float*)d_in[1];
  const float* W_emb = (const float*)d_in[2];
  const float* b_emb = (const float*)d_in[3];
  const float* Wx1   = (const float*)d_in[4];
  const float* bx1   = (const float*)d_in[5];
  const float* Wx2   = (const float*)d_in[6];
  const float* bx2   = (const float*)d_in[7];
  const float* Wx3   = (const float*)d_in[8];
  const float* bx3   = (const float*)d_in[9];
  const float* W_ih  = (const float*)d_in[10];
  const float* W_hh  = (const float*)d_in[11];
  const float* b_ih  = (const float*)d_in[12];
  const float* b_hh  = (const float*)d_in[13];
  const float* W_out = (const float*)d_in[14];
  const float* b_out = (const float*)d_in[15];
  float* out = (float*)d_out;
  unsigned char* ws = (unsigned char*)d_ws;

  if (ws_size < (size_t)WS_END) return;

  float*    e1tmp   = (float*)(ws + HLAST_B);      // shared with Hlast
  float*    Hlast   = (float*)(ws + HLAST_B);
  uint16_t* E_mlp   = (uint16_t*)(ws + EMLP_B);
  uint16_t* h_state = (uint16_t*)(ws + HSTATE_B);
  uint16_t* h_emb   = (uint16_t*)(ws + HEMB_B);
  float*    c_state = (float*)(ws + CSTATE_B);

  k_init<<<(NL_ * L_ * B_) / 256, 256, 0, stream>>>(z0, h_state, c_state);
  k_mlp1<<<255 * 4, 256, 0, stream>>>(obsrv, Wx1, bx1, e1tmp);
  k_mlp2<<<255, 256, 0, stream>>>(e1tmp, Wx2, bx2, Wx3, bx3, E_mlp);

  void* args[] = {(void*)&W_emb, (void*)&b_emb, (void*)&W_ih, (void*)&W_hh,
                  (void*)&b_ih, (void*)&b_hh, (void*)&h_state, (void*)&h_emb,
                  (void*)&E_mlp, (void*)&c_state, (void*)&Hlast};
  hipLaunchCooperativeKernel((const void*)k_wave, dim3(NL_ * 8), dim3(512),
                             args, 0, stream);

  k_final<<<S_ * 4, 256, 0, stream>>>(Hlast, W_out, b_out, out);
}

// Round 4
// 17580.597 us; speedup vs baseline: 4.4546x; 1.0695x over previous
//
#include <hip/hip_runtime.h>
#include <hip/hip_cooperative_groups.h>
#include <stdint.h>

namespace cg = cooperative_groups;

// ---------------------------------------------------------------------------
// LIDM forward, round 4: W_emb fused into gates (Wf = W_hh@W_emb), one phase +
// one grid.sync per diagonal; noise GEMM pipelined one diagonal ahead;
// B-fragments read directly from global (L3), no B staging.
// ---------------------------------------------------------------------------
#ifndef NOISE_VARIANT
#define NOISE_VARIANT 0
#endif

#define S_ 256
#define B_ 64
#define O_ 128
#define L_ 256
#define NL_ 25

typedef __attribute__((ext_vector_type(8))) short short8v;
typedef __attribute__((ext_vector_type(16))) float f32x16;

// ---- workspace byte offsets ----
#define SH_B    0u          // u16: e1 [256][256][64] (mlp temp) / Hlast [256][256][64]
#define EMLP_B  8388608u    // u16 [256][64][256]
#define HST_B   16777216u   // u16 [2][25][64][256]
#define CST_B   18415616u   // f32 [25][256][64]
#define WF_B    20054016u   // u16 [25][1024][256]
#define BIASF_B 33161216u   // f32 [25][1024]
#define WS_END  33263616u

// ---------------------------- helpers --------------------------------------
__device__ __forceinline__ uint16_t f2bf(float x) {
  uint32_t u = __float_as_uint(x);
  return (uint16_t)((u + 0x7fffu + ((u >> 16) & 1u)) >> 16);
}
__device__ __forceinline__ float bf2f(uint16_t u) {
  return __uint_as_float(((uint32_t)u) << 16);
}
__device__ __forceinline__ short8v pack8(float4 a, float4 b) {
  short8v w;
  w[0] = (short)f2bf(a.x); w[1] = (short)f2bf(a.y);
  w[2] = (short)f2bf(a.z); w[3] = (short)f2bf(a.w);
  w[4] = (short)f2bf(b.x); w[5] = (short)f2bf(b.y);
  w[6] = (short)f2bf(b.z); w[7] = (short)f2bf(b.w);
  return w;
}

__device__ __forceinline__ uint32_t rotl32(uint32_t v, int r) {
  return (v << r) | (v >> (32 - r));
}

__device__ __forceinline__ void tf2x32(uint32_t k0, uint32_t k1,
                                       uint32_t x0, uint32_t x1,
                                       uint32_t& o0, uint32_t& o1) {
  uint32_t ks2 = k0 ^ k1 ^ 0x1BD11BDAu;
  x0 += k0; x1 += k1;
  x0 += x1; x1 = rotl32(x1, 13); x1 ^= x0;
  x0 += x1; x1 = rotl32(x1, 15); x1 ^= x0;
  x0 += x1; x1 = rotl32(x1, 26); x1 ^= x0;
  x0 += x1; x1 = rotl32(x1,  6); x1 ^= x0;
  x0 += k1; x1 += ks2 + 1u;
  x0 += x1; x1 = rotl32(x1, 17); x1 ^= x0;
  x0 += x1; x1 = rotl32(x1, 29); x1 ^= x0;
  x0 += x1; x1 = rotl32(x1, 16); x1 ^= x0;
  x0 += x1; x1 = rotl32(x1, 24); x1 ^= x0;
  x0 += ks2; x1 += k0 + 2u;
  x0 += x1; x1 = rotl32(x1, 13); x1 ^= x0;
  x0 += x1; x1 = rotl32(x1, 15); x1 ^= x0;
  x0 += x1; x1 = rotl32(x1, 26); x1 ^= x0;
  x0 += x1; x1 = rotl32(x1,  6); x1 ^= x0;
  x0 += k0; x1 += k1 + 3u;
  x0 += x1; x1 = rotl32(x1, 17); x1 ^= x0;
  x0 += x1; x1 = rotl32(x1, 29); x1 ^= x0;
  x0 += x1; x1 = rotl32(x1, 16); x1 ^= x0;
  x0 += x1; x1 = rotl32(x1, 24); x1 ^= x0;
  x0 += k1; x1 += ks2 + 4u;
  x0 += x1; x1 = rotl32(x1, 13); x1 ^= x0;
  x0 += x1; x1 = rotl32(x1, 15); x1 ^= x0;
  x0 += x1; x1 = rotl32(x1, 26); x1 ^= x0;
  x0 += x1; x1 = rotl32(x1,  6); x1 ^= x0;
  o0 = x0 + ks2; o1 = x1 + k0 + 5u;
}

__device__ __forceinline__ void step_keys(int k, uint32_t& kh0, uint32_t& kh1,
                                          uint32_t& kx0, uint32_t& kx1) {
  uint32_t f0, f1;
  tf2x32(0u, 42u, 0u, (uint32_t)k, f0, f1);
#if NOISE_VARIANT == 0
  tf2x32(f0, f1, 0u, 0u, kh0, kh1);
  tf2x32(f0, f1, 0u, 1u, kx0, kx1);
#else
  uint32_t a0, a1, b0, b1;
  tf2x32(f0, f1, 0u, 2u, a0, a1);
  tf2x32(f0, f1, 1u, 3u, b0, b1);
  kh0 = a0; kh1 = b0; kx0 = a1; kx1 = b1;
#endif
}

__device__ __forceinline__ uint32_t rbits(uint32_t key0, uint32_t key1,
                                          uint32_t i) {
  uint32_t b0, b1;
  tf2x32(key0, key1, 0u, i, b0, b1);
  return b0 ^ b1;
}

__device__ __forceinline__ float u32_to_normal(uint32_t bits) {
  const float lo = __uint_as_float(0xBF7FFFFFu);
  float f = __uint_as_float((bits >> 9) | 0x3F800000u) - 1.0f;
  float u = f * 2.0f + lo;
  u = fmaxf(lo, u);
  float x = u;
  float w = -log1pf(-x * x);
  float p;
  if (w < 5.0f) {
    w -= 2.5f;
    p =            2.81022636e-08f;
    p = fmaf(p, w, 3.43273939e-07f);
    p = fmaf(p, w, -3.5233877e-06f);
    p = fmaf(p, w, -4.39150654e-06f);
    p = fmaf(p, w, 0.00021858087f);
    p = fmaf(p, w, -0.00125372503f);
    p = fmaf(p, w, -0.00417768164f);
    p = fmaf(p, w, 0.246640727f);
    p = fmaf(p, w, 1.50140941f);
  } else {
    w = sqrtf(w) - 3.0f;
    p =            -0.000200214257f;
    p = fmaf(p, w, 0.000100950558f);
    p = fmaf(p, w, 0.00134934322f);
    p = fmaf(p, w, -0.00367342844f);
    p = fmaf(p, w, 0.00573950773f);
    p = fmaf(p, w, -0.0076224613f);
    p = fmaf(p, w, 0.00943887047f);
    p = fmaf(p, w, 1.00167406f);
    p = fmaf(p, w, 2.83297682f);
  }
  return __uint_as_float(0x3FB504F3u) * (p * x);
}

__device__ __forceinline__ float sigm(float x) { return 1.0f / (1.0f + expf(-x)); }

// ------------------------------- prep kernels ------------------------------

// h_state[0] = bf16(z0) (flat [l][b][j]); c_state = 0
__global__ __launch_bounds__(256) void k_init(const float* __restrict__ z0,
                                              uint16_t* __restrict__ hs0,
                                              float* __restrict__ c_state) {
  int idx = blockIdx.x * 256 + threadIdx.x;
  hs0[idx] = f2bf(z0[idx]);
  c_state[idx] = 0.0f;
}

// Wf[l] = W_hh[l] @ W_emb  (f32 accumulate, bf16 out). grid 25*16, 256 thr.
__global__ __launch_bounds__(256) void k_wf(const float* __restrict__ Whh,
                                            const float* __restrict__ Wemb,
                                            uint16_t* __restrict__ Wf) {
  __shared__ float Bs[32][256];
  int l = blockIdx.x >> 4, rt = blockIdx.x & 15;
  int j = threadIdx.x;
  float acc[64];
#pragma unroll
  for (int r = 0; r < 64; ++r) acc[r] = 0.0f;
  const float* Abase = Whh + ((size_t)l * 1024 + rt * 64) * 256;
  for (int m0 = 0; m0 < 256; m0 += 32) {
    __syncthreads();
    {
      int rr = threadIdx.x >> 3, cseg = threadIdx.x & 7;
      const float* src = Wemb + (size_t)(m0 + rr) * 256 + cseg * 32;
      float* dst = &Bs[rr][cseg * 32];
#pragma unroll
      for (int q = 0; q < 8; ++q)
        reinterpret_cast<float4*>(dst)[q] = reinterpret_cast<const float4*>(src)[q];
    }
    __syncthreads();
    for (int mm = 0; mm < 32; ++mm) {
      float bj = Bs[mm][j];
      const float* Acol = Abase + m0 + mm;
#pragma unroll
      for (int r = 0; r < 64; ++r) acc[r] = fmaf(Acol[r * 256], bj, acc[r]);
    }
  }
  for (int r = 0; r < 64; ++r)
    Wf[((size_t)l * 1024 + rt * 64 + r) * 256 + j] = f2bf(acc[r]);
}

// biasf[l][gi] = b_ih + b_hh + W_hh[l][gi] . b_emb   grid 100, 256 thr
__global__ __launch_bounds__(256) void k_biasf(const float* __restrict__ Whh,
                                               const float* __restrict__ bemb,
                                               const float* __restrict__ bih,
                                               const float* __restrict__ bhh,
                                               float* __restrict__ biasf) {
  int l = blockIdx.x >> 2;
  int gi = (blockIdx.x & 3) * 256 + threadIdx.x;
  const float* row = Whh + ((size_t)l * 1024 + gi) * 256;
  float a = 0.0f;
  for (int m = 0; m < 256; ++m) a = fmaf(row[m], bemb[m], a);
  biasf[l * 1024 + gi] = a + bih[l * 1024 + gi] + bhh[l * 1024 + gi];
}

// e1[k][j][b] = relu(obsrv[k] @ Wx1^T + bx1)  bf16 out, grid 255*4
__global__ __launch_bounds__(256) void k_mlp1(const float* __restrict__ obsrv,
                                              const float* __restrict__ Wx1,
                                              const float* __restrict__ bx1,
                                              uint16_t* __restrict__ e1out) {
  int k = 1 + (blockIdx.x >> 2);
  int jc = blockIdx.x & 3;
  int lane = threadIdx.x & 63;
  int wv = threadIdx.x >> 6;
  int j0 = jc * 64 + wv * 16;
  const float* xrow = obsrv + ((size_t)k * B_ + lane) * O_;
  float acc[16];
#pragma unroll
  for (int i = 0; i < 16; ++i) acc[i] = 0.0f;
  for (int o = 0; o < O_; o += 4) {
    float4 a = *reinterpret_cast<const float4*>(&xrow[o]);
#pragma unroll
    for (int mi = 0; mi < 16; ++mi) {
      float4 wt = *reinterpret_cast<const float4*>(&Wx1[(size_t)(j0 + mi) * O_ + o]);
      float t = acc[mi];
      t = fmaf(a.x, wt.x, t); t = fmaf(a.y, wt.y, t);
      t = fmaf(a.z, wt.z, t); t = fmaf(a.w, wt.w, t);
      acc[mi] = t;
    }
  }
  uint16_t* dst = e1out + (size_t)k * L_ * B_;
#pragma unroll
  for (int mi = 0; mi < 16; ++mi) {
    float v = acc[mi] + bx1[j0 + mi];
    dst[(j0 + mi) * B_ + lane] = f2bf(fmaxf(v, 0.0f));
  }
}

// MLP layers 2,3 + sqrt(alpha)*e + 0.1*noise -> E_mlp bf16 [k][b][j]
__global__ __launch_bounds__(256) void k_mlp2(const uint16_t* __restrict__ e1buf,
                                              const float* __restrict__ Wx2,
                                              const float* __restrict__ bx2,
                                              const float* __restrict__ Wx3,
                                              const float* __restrict__ bx3,
                                              uint16_t* __restrict__ E_mlp) {
  __shared__ float e2s[L_ * B_];
  int k = 1 + blockIdx.x;
  int lane = threadIdx.x & 63;
  int wv = threadIdx.x >> 6;
  const uint16_t* e1 = e1buf + (size_t)k * L_ * B_;

  for (int rep = 0; rep < 4; ++rep) {
    int m0 = rep * 64 + wv * 16;
    float acc[16];
#pragma unroll
    for (int i = 0; i < 16; ++i) acc[i] = 0.0f;
    for (int j = 0; j < L_; j += 4) {
      float a0 = bf2f(e1[(j + 0) * B_ + lane]);
      float a1 = bf2f(e1[(j + 1) * B_ + lane]);
      float a2 = bf2f(e1[(j + 2) * B_ + lane]);
      float a3 = bf2f(e1[(j + 3) * B_ + lane]);
#pragma unroll
      for (int mi = 0; mi < 16; ++mi) {
        float4 wt = *reinterpret_cast<const float4*>(&Wx2[(size_t)(m0 + mi) * L_ + j]);
        float t = acc[mi];
        t = fmaf(a0, wt.x, t); t = fmaf(a1, wt.y, t);
        t = fmaf(a2, wt.z, t); t = fmaf(a3, wt.w, t);
        acc[mi] = t;
      }
    }
#pragma unroll
    for (int mi = 0; mi < 16; ++mi) {
      float v = acc[mi] + bx2[m0 + mi];
      e2s[(m0 + mi) * B_ + lane] = fmaxf(v, 0.0f);
    }
  }
  __syncthreads();

  uint32_t kh0, kh1, kx0, kx1;
  step_keys(k, kh0, kh1, kx0, kx1);
  const float sa = sqrtf(0.9f);

  for (int rep = 0; rep < 4; ++rep) {
    int m0 = rep * 64 + wv * 16;
    float acc[16];
#pragma unroll
    for (int i = 0; i < 16; ++i) acc[i] = 0.0f;
    for (int j = 0; j < L_; j += 4) {
      float a0 = e2s[(j + 0) * B_ + lane];
      float a1 = e2s[(j + 1) * B_ + lane];
      float a2 = e2s[(j + 2) * B_ + lane];
      float a3 = e2s[(j + 3) * B_ + lane];
#pragma unroll
      for (int mi = 0; mi < 16; ++mi) {
        float4 wt = *reinterpret_cast<const float4*>(&Wx3[(size_t)(m0 + mi) * L_ + j]);
        float t = acc[mi];
        t = fmaf(a0, wt.x, t); t = fmaf(a1, wt.y, t);
        t = fmaf(a2, wt.z, t); t = fmaf(a3, wt.w, t);
        acc[mi] = t;
      }
    }
    uint16_t tmp[16];
#pragma unroll
    for (int mi = 0; mi < 16; ++mi) {
      int m = m0 + mi;
      float nz = u32_to_normal(rbits(kx0, kx1, (uint32_t)(lane * L_ + m)));
      tmp[mi] = f2bf(sa * (acc[mi] + bx3[m]) + 0.1f * nz);
    }
    uint16_t* dst = E_mlp + ((size_t)k * B_ + lane) * L_ + m0;
    *reinterpret_cast<uint4*>(dst) = *reinterpret_cast<const uint4*>(&tmp[0]);
    *reinterpret_cast<uint4*>(dst + 8) = *reinterpret_cast<const uint4*>(&tmp[8]);
  }
}

// ------------------------------ wavefront ----------------------------------
// 200 blocks x 512 thr; block = (l = bid>>3, s = bid&7); LDS 147456 B.
__global__ __launch_bounds__(512, 1) void k_wave(
    const uint16_t* __restrict__ Wf, const float* __restrict__ W_ih,
    const float* __restrict__ W_hh, const float* __restrict__ biasf,
    uint16_t* __restrict__ hstate, const uint16_t* __restrict__ emlp,
    float* __restrict__ cstate, uint16_t* __restrict__ hlast) {
  cg::grid_group grid = cg::this_grid();
  __shared__ __align__(16) unsigned char WAF[65536];  // Wf slice [128 r][512B] swz
  __shared__ __align__(16) unsigned char WAI[65536];  // W_ih slice
  __shared__ __align__(16) unsigned char V[16384];    // noise half-panel [64 b][256B] swz

  const int bid = blockIdx.x;
  const int l = bid >> 3;
  const int s = bid & 7;
  const int t = threadIdx.x;
  const int lane = t & 63;
  const int wid = t >> 6;
  const int lo5 = lane & 31;
  const int hi = lane >> 5;
  const int tm = wid >> 1;
  const int tn = wid & 1;
  const int bcol = tn * 32 + lo5;                 // B-operand row (batch col)
  const int arow = tm * 32 + lo5;                 // A row within slice
  const int aswz = (arow & 7) << 4;
  const int gi_a = (arow & 3) * 256 + s * 32 + (arow >> 5) * 8 + ((arow >> 2) & 7);
  const int bswz = (bcol & 7) << 4;

  // pack Wf (bf16) and W_ih (f32) slices into LDS, XOR-swizzled
  for (int it = 0; it < 8; ++it) {
    int c = it * 512 + t;
    int r = c >> 5, cc = c & 31;
    int gi = (r & 3) * 256 + s * 32 + (r >> 5) * 8 + ((r >> 2) & 7);
    uint4 v = *reinterpret_cast<const uint4*>(Wf + ((size_t)l * 1024 + gi) * 256 + cc * 8);
    *reinterpret_cast<uint4*>(WAF + r * 512 + ((cc * 16) ^ ((r & 7) << 4))) = v;
  }
  for (int it = 0; it < 8; ++it) {
    int c = it * 512 + t;
    int r = c >> 5, cc = c & 31;
    int gi = (r & 3) * 256 + s * 32 + (r >> 5) * 8 + ((r >> 2) & 7);
    const float* sr = W_ih + ((size_t)l * 1024 + gi) * 256 + cc * 8;
    float4 f0 = *reinterpret_cast<const float4*>(sr);
    float4 f1 = *reinterpret_cast<const float4*>(sr + 4);
    *reinterpret_cast<short8v*>(WAI + r * 512 + ((cc * 16) ^ ((r & 7) << 4))) = pack8(f0, f1);
  }
  __syncthreads();

  f32x16 acc_nb = {0,0,0,0,0,0,0,0,0,0,0,0,0,0,0,0};

  for (int d = 0; d <= 279; ++d) {
    const int k = d - l;
    const bool gact = (k >= 1 && k <= 255);
    const bool nact = (k >= 0 && k <= 254);

    if (gact) {
      const uint16_t* hp = hstate + (((size_t)((k - 1) & 1) * NL_ + l) << 14);
      const uint16_t* ip = (l == 0)
          ? (emlp + ((size_t)k << 14))
          : (hstate + (((size_t)(k & 1) * NL_ + (l - 1)) << 14));
      f32x16 acc = {0,0,0,0,0,0,0,0,0,0,0,0,0,0,0,0};
#pragma unroll 4
      for (int kt = 0; kt < 16; ++kt) {
        short8v bv = *reinterpret_cast<const short8v*>(hp + bcol * 256 + kt * 16 + hi * 8);
        short8v av = *reinterpret_cast<const short8v*>(WAF + arow * 512 + ((kt * 32 + hi * 16) ^ aswz));
        acc = __builtin_amdgcn_mfma_f32_32x32x16_bf16(av, bv, acc, 0, 0, 0);
      }
#pragma unroll 4
      for (int kt = 0; kt < 16; ++kt) {
        short8v bv = *reinterpret_cast<const short8v*>(ip + bcol * 256 + kt * 16 + hi * 8);
        short8v av = *reinterpret_cast<const short8v*>(WAI + arow * 512 + ((kt * 32 + hi * 16) ^ aswz));
        acc = __builtin_amdgcn_mfma_f32_32x32x16_bf16(av, bv, acc, 0, 0, 0);
      }
      // epilogue: gates = acc + acc_nb(prev diag) + biasf
      uint16_t* hd = hstate + (((size_t)(k & 1) * NL_ + l) << 14);
      const float* bf = biasf + l * 1024;
#pragma unroll
      for (int mq = 0; mq < 4; ++mq) {
        int mi = s * 32 + tm * 8 + mq * 2 + hi;
        float iv = acc[4 * mq + 0] + acc_nb[4 * mq + 0] + bf[mi];
        float fv = acc[4 * mq + 1] + acc_nb[4 * mq + 1] + bf[256 + mi];
        float gv = acc[4 * mq + 2] + acc_nb[4 * mq + 2] + bf[512 + mi];
        float ov = acc[4 * mq + 3] + acc_nb[4 * mq + 3] + bf[768 + mi];
        size_t cidx = ((size_t)l * 256 + mi) * 64 + bcol;
        float co = cstate[cidx];
        float cn = sigm(fv) * co + sigm(iv) * tanhf(gv);
        float hn = sigm(ov) * tanhf(cn);
        cstate[cidx] = cn;
        hd[bcol * 256 + mi] = f2bf(hn);
        if (l == NL_ - 1) hlast[((size_t)k << 14) + mi * 64 + bcol] = f2bf(hn);
      }
    }

    if (nact) {
      const int k1 = k + 1;
      uint32_t kh0, kh1, kx0, kx1;
      step_keys(k1, kh0, kh1, kx0, kx1);
      f32x16 nbn = {0,0,0,0,0,0,0,0,0,0,0,0,0,0,0,0};
      const int vb = t >> 3;
      const int vch = (t & 7) * 2;
      const int vswz = (vb & 7) << 4;
      const uint32_t ibase = ((uint32_t)(l * 64 + vb)) * 256;
#pragma unroll
      for (int hf = 0; hf < 2; ++hf) {
        __syncthreads();
        uint32_t pw[8];
#pragma unroll
        for (int w = 0; w < 8; ++w) {
          int ch = vch + (w >> 2);
          int j0 = hf * 128 + ch * 8 + (w & 3) * 2;
          uint16_t v0 = f2bf(0.1f * u32_to_normal(rbits(kh0, kh1, ibase + j0)));
          uint16_t v1 = f2bf(0.1f * u32_to_normal(rbits(kh0, kh1, ibase + j0 + 1)));
          pw[w] = (uint32_t)v0 | ((uint32_t)v1 << 16);
        }
        uint4 q0 = make_uint4(pw[0], pw[1], pw[2], pw[3]);
        uint4 q1 = make_uint4(pw[4], pw[5], pw[6], pw[7]);
        *reinterpret_cast<uint4*>(V + vb * 256 + ((vch * 16) ^ vswz)) = q0;
        *reinterpret_cast<uint4*>(V + vb * 256 + (((vch + 1) * 16) ^ vswz)) = q1;
        __syncthreads();
#pragma unroll 2
        for (int kt = 0; kt < 8; ++kt) {
          int j = hf * 128 + kt * 16 + hi * 8;
          const float* wr = W_hh + ((size_t)l * 1024 + gi_a) * 256 + j;
          float4 f0 = *reinterpret_cast<const float4*>(wr);
          float4 f1 = *reinterpret_cast<const float4*>(wr + 4);
          short8v av = pack8(f0, f1);
          short8v bv = *reinterpret_cast<const short8v*>(V + bcol * 256 + ((kt * 32 + hi * 16) ^ bswz));
          nbn = __builtin_amdgcn_mfma_f32_32x32x16_bf16(av, bv, nbn, 0, 0, 0);
        }
      }
      acc_nb = nbn;
    }

    grid.sync();
  }
}

// out[k][b][m] = Hlast[k] @ W_out^T + b_out ; out[0] = 0   (grid 256*4)
__global__ __launch_bounds__(256) void k_final(const uint16_t* __restrict__ Hlast,
                                               const float* __restrict__ W_out,
                                               const float* __restrict__ b_out,
                                               float* __restrict__ out) {
  int k = blockIdx.x >> 2;
  int mc = blockIdx.x & 3;
  int lane = threadIdx.x & 63;
  int wv = threadIdx.x >> 6;
  int m0 = mc * 64 + wv * 16;
  float res[16];
  if (k == 0) {
#pragma unroll
    for (int mi = 0; mi < 16; ++mi) res[mi] = 0.0f;
  } else {
    float acc[16];
#pragma unroll
    for (int i = 0; i < 16; ++i) acc[i] = 0.0f;
    const uint16_t* src = Hlast + ((size_t)k << 14);
    for (int j = 0; j < L_; j += 4) {
      float a0 = bf2f(src[(j + 0) * B_ + lane]);
      float a1 = bf2f(src[(j + 1) * B_ + lane]);
      float a2 = bf2f(src[(j + 2) * B_ + lane]);
      float a3 = bf2f(src[(j + 3) * B_ + lane]);
#pragma unroll
      for (int mi = 0; mi < 16; ++mi) {
        float4 wt = *reinterpret_cast<const float4*>(&W_out[(size_t)(m0 + mi) * L_ + j]);
        float t = acc[mi];
        t = fmaf(a0, wt.x, t); t = fmaf(a1, wt.y, t);
        t = fmaf(a2, wt.z, t); t = fmaf(a3, wt.w, t);
        acc[mi] = t;
      }
    }
#pragma unroll
    for (int mi = 0; mi < 16; ++mi) res[mi] = acc[mi] + b_out[m0 + mi];
  }
  float* dst = out + ((size_t)k * B_ + lane) * L_ + m0;
#pragma unroll
  for (int v = 0; v < 4; ++v) {
    float4 t4 = make_float4(res[4 * v], res[4 * v + 1], res[4 * v + 2], res[4 * v + 3]);
    *reinterpret_cast<float4*>(&dst[4 * v]) = t4;
  }
}

// ------------------------------ launcher -----------------------------------
extern "C" void kernel_launch(void* const* d_in, const int* in_sizes, int n_in,
                              void* d_out, int out_size, void* d_ws, size_t ws_size,
                              hipStream_t stream) {
  const float* obsrv = (const float*)d_in[0];
  const float* z0    = (const float*)d_in[1];
  const float* W_emb = (const float*)d_in[2];
  const float* b_emb = (const float*)d_in[3];
  const float* Wx1   = (const float*)d_in[4];
  const float* bx1   = (const float*)d_in[5];
  const float* Wx2   = (const float*)d_in[6];
  const float* bx2   = (const float*)d_in[7];
  const float* Wx3   = (const float*)d_in[8];
  const float* bx3   = (const float*)d_in[9];
  const float* W_ih  = (const float*)d_in[10];
  const float* W_hh  = (const float*)d_in[11];
  const float* b_ih  = (const float*)d_in[12];
  const float* b_hh  = (const float*)d_in[13];
  const float* W_out = (const float*)d_in[14];
  const float* b_out = (const float*)d_in[15];
  float* out = (float*)d_out;
  unsigned char* ws = (unsigned char*)d_ws;

  if (ws_size < (size_t)WS_END) return;

  uint16_t* e1tmp   = (uint16_t*)(ws + SH_B);
  uint16_t* Hlast   = (uint16_t*)(ws + SH_B);
  uint16_t* E_mlp   = (uint16_t*)(ws + EMLP_B);
  uint16_t* h_state = (uint16_t*)(ws + HST_B);
  float*    c_state = (float*)(ws + CST_B);
  uint16_t* Wf      = (uint16_t*)(ws + WF_B);
  float*    biasf   = (float*)(ws + BIASF_B);

  k_init<<<(NL_ * L_ * B_) / 256, 256, 0, stream>>>(z0, h_state, c_state);
  k_wf<<<25 * 16, 256, 0, stream>>>(W_hh, W_emb, Wf);
  k_biasf<<<25 * 4, 256, 0, stream>>>(W_hh, b_emb, b_ih, b_hh, biasf);
  k_mlp1<<<255 * 4, 256, 0, stream>>>(obsrv, Wx1, bx1, e1tmp);
  k_mlp2<<<255, 256, 0, stream>>>(e1tmp, Wx2, bx2, Wx3, bx3, E_mlp);

  void* args[] = {(void*)&Wf, (void*)&W_ih, (void*)&W_hh, (void*)&biasf,
                  (void*)&h_state, (void*)&E_mlp, (void*)&c_state, (void*)&Hlast};
  hipLaunchCooperativeKernel((const void*)k_wave, dim3(NL_ * 8), dim3(512),
                             args, 0, stream);

  k_final<<<S_ * 4, 256, 0, stream>>>(Hlast, W_out, b_out, out);
}